// Round 6
// baseline (119.115 us; speedup 1.0000x reference)
//
#include <hip/hip_runtime.h>
#include <stdint.h>

#define SEQ 2048
#define QSCALE 0.1803368801111244f   // 0.125 * log2(e)
#define DEFER_THR 11.5f              // 8 nats in log2 units

typedef __attribute__((ext_vector_type(8))) short bf16x8;
typedef __attribute__((ext_vector_type(4))) short bf16x4;
typedef __attribute__((ext_vector_type(4))) float f32x4;
typedef __attribute__((ext_vector_type(16))) float f32x16;
typedef unsigned short u16;

__device__ __forceinline__ u16 f2bf(float f) {
  union { float f; uint32_t u; } v; v.f = f;
  uint32_t u = v.u;
  u += 0x7fffu + ((u >> 16) & 1u);   // RNE
  return (u16)(u >> 16);
}

__device__ __forceinline__ float fast_exp2(float x) {
#if __has_builtin(__builtin_amdgcn_exp2f)
  return __builtin_amdgcn_exp2f(x);   // v_exp_f32 (native base-2)
#else
  return exp2f(x);
#endif
}

__device__ __forceinline__ uint32_t cvtpk(float a, float b) {
  uint32_t r;
  asm("v_cvt_pk_bf16_f32 %0, %1, %2" : "=v"(r) : "v"(a), "v"(b));
  return r;
}

// exchange across lane<->lane^32 (verified semantics, R5):
// a' = (hi ? partner_b : a), b' = (hi ? b : partner_a)
__device__ __forceinline__ void swap_pair(uint32_t& a, uint32_t& b, int hi) {
  uint32_t ta = (uint32_t)__shfl_xor((int)a, 32);
  uint32_t tb = (uint32_t)__shfl_xor((int)b, 32);
  a = hi ? tb : a;
  b = hi ? b : ta;
}

__device__ __forceinline__ void gload_lds16(const u16* g, u16* l) {
  __builtin_amdgcn_global_load_lds((__attribute__((address_space(1))) void*)g,
                                   (__attribute__((address_space(3))) void*)l,
                                   16, 0, 0);
}

// ---------------- fused fp32 -> bf16 convert (all 5 tensors, 1 launch) -----
__global__ void cvt5_kernel(const float* __restrict__ x, const float* __restrict__ z,
                            const float* __restrict__ Wq, const float* __restrict__ Wkv,
                            const float* __restrict__ Wo,
                            u16* __restrict__ xb, u16* __restrict__ zb,
                            u16* __restrict__ wqb, u16* __restrict__ wkvb,
                            u16* __restrict__ wob) {
  const int X4 = 1048576, Z4 = 524288, W4 = 262144;
  const int total = X4 + Z4 + 3 * W4;
  int i = blockIdx.x * blockDim.x + threadIdx.x;
  const int stride = gridDim.x * blockDim.x;
  for (; i < total; i += stride) {
    const float* src; u16* dst; int j = i;
    if (j < X4)              { src = x;   dst = xb; }
    else if ((j -= X4) < Z4) { src = z;   dst = zb; }
    else if ((j -= Z4) < W4) { src = Wq;  dst = wqb; }
    else if ((j -= W4) < W4) { src = Wkv; dst = wkvb; }
    else       { j -= W4;      src = Wo;  dst = wob; }
    float4 v = ((const float4*)src)[j];
    bf16x4 o;
    o[0] = (short)f2bf(v.x); o[1] = (short)f2bf(v.y);
    o[2] = (short)f2bf(v.z); o[3] = (short)f2bf(v.w);
    ((bf16x4*)dst)[j] = o;
  }
}

// ---------------- C = scale * A(MxK) @ B(NxK)^T body, 128xBN tile ----------
template <int BN, typename CT>
__device__ __forceinline__ void gemm_bt_body(const u16* __restrict__ A,
                                             const u16* __restrict__ B,
                                             CT* __restrict__ C,
                                             int N, int K, float scale,
                                             int tm, int tn, u16* As, u16* Bs) {
  constexpr int NB = BN / 32;    // N-fragments per wave
  constexpr int NBG = BN / 64;   // B staging gloads
  const int tid = threadIdx.x;
  const int wid = tid >> 6;
  const int lane = tid & 63;
  const int lg = lane >> 4, lq = lane & 15;
  const int wr = wid >> 1, wc = wid & 1;

  f32x4 acc[4][NB];
#pragma unroll
  for (int m = 0; m < 4; m++)
#pragma unroll
    for (int n = 0; n < NB; n++)
#pragma unroll
      for (int e = 0; e < 4; e++) acc[m][n][e] = 0.f;

  const int r0 = tid >> 2;
  const int s0 = tid & 3;
  const int sc = (s0 ^ ((r0 >> 1) & 3)) * 8;
  const u16* gA0 = A + (size_t)(tm * 128 + r0) * K + sc;
  const u16* gA1 = gA0 + (size_t)64 * K;
  const u16* gB0 = B + (size_t)(tn * BN + r0) * K + sc;
  const u16* gB1 = gB0 + (size_t)64 * K;
  u16* lA = As + wid * 512;
  u16* lB = Bs + wid * 512;

  const int rslot = (lg ^ ((lq >> 1) & 3)) * 8;

  for (int k0 = 0; k0 < K; k0 += 32) {
    __syncthreads();
    gload_lds16(gA0 + k0, lA);
    gload_lds16(gA1 + k0, lA + 2048);
    gload_lds16(gB0 + k0, lB);
    if constexpr (NBG == 2) gload_lds16(gB1 + k0, lB + 2048);
    __syncthreads();

    bf16x8 af[4], bfr[NB];
#pragma unroll
    for (int m = 0; m < 4; m++)
      af[m] = *(const bf16x8*)(As + (wr * 64 + m * 16 + lq) * 32 + rslot);
#pragma unroll
    for (int n = 0; n < NB; n++)
      bfr[n] = *(const bf16x8*)(Bs + (wc * (BN / 2) + n * 16 + lq) * 32 + rslot);
#pragma unroll
    for (int m = 0; m < 4; m++)
#pragma unroll
      for (int n = 0; n < NB; n++)
        acc[m][n] = __builtin_amdgcn_mfma_f32_16x16x32_bf16(af[m], bfr[n], acc[m][n], 0, 0, 0);
  }

#pragma unroll
  for (int m = 0; m < 4; m++) {
    const int row = tm * 128 + wr * 64 + m * 16 + lg * 4;
#pragma unroll
    for (int i = 0; i < 4; i++) {
      CT* cp = C + (size_t)(row + i) * N + tn * BN + wc * (BN / 2) + lq;
#pragma unroll
      for (int n = 0; n < NB; n++) {
        float v = acc[m][n][i] * scale;
        if constexpr (sizeof(CT) == 2) cp[n * 16] = (CT)f2bf(v);
        else                            cp[n * 16] = (CT)v;
      }
    }
  }
}

// ---------------- fused Q/K/VT projection GEMMs (768 blocks) ----------------
__global__ __launch_bounds__(256) void qkv_gemm(const u16* __restrict__ xb,
                                                const u16* __restrict__ zb,
                                                const u16* __restrict__ Wqb,
                                                const u16* __restrict__ Wkvb,
                                                u16* __restrict__ Qb,
                                                u16* __restrict__ Kb,
                                                u16* __restrict__ VTb) {
  __shared__ __align__(16) u16 As[128 * 32];
  __shared__ __align__(16) u16 Bs[128 * 32];
  int g = blockIdx.x;
  if (g < 256) {
    // Q = (0.125*log2e) * x @ Wq^T   [4096 x 1024]
    gemm_bt_body<128, u16>(xb, Wqb, Qb, 1024, 1024, QSCALE, g >> 3, g & 7, As, Bs);
  } else if (g < 512) {
    g -= 256;  // K = z @ Wk^T   [4096 x 1024]
    gemm_bt_body<128, u16>(zb, Wkvb, Kb, 1024, 512, 1.f, g >> 3, g & 7, As, Bs);
  } else {
    g -= 512;  // VT = Wv @ z^T  [1024 x 4096]
    gemm_bt_body<128, u16>(Wkvb + 1024 * 512, zb, VTb, 4096, 512, 1.f, g >> 5, g & 31, As, Bs);
  }
}

// ---------------- O-GEMM: out = O @ Wo^T, fp32 out, 128x64 tiles ------------
__global__ __launch_bounds__(256) void o_gemm(const u16* __restrict__ Ob,
                                              const u16* __restrict__ Wob,
                                              float* __restrict__ out) {
  __shared__ __align__(16) u16 As[128 * 32];
  __shared__ __align__(16) u16 Bs[64 * 32];
  gemm_bt_body<64, float>(Ob, Wob, out, 1024, 1024, 1.f, blockIdx.y, blockIdx.x, As, Bs);
}

// ---------------- flash attention (32x32 MFMA, QK pipelined 1 tile ahead) ---
// Q : [B*SEQ][1024] bf16, pre-scaled by 0.125*log2e
// K : [B*SEQ][1024] bf16
// VT: [1024][B*SEQ]  bf16
// O : [B*SEQ][1024] bf16
// 512 blocks, 4 waves x 32 q = 128 q/block. LDS u16: Kb0@0 Kb1@4096 Vb0@8192 Vb1@12288.
__global__ __launch_bounds__(256, 2) void attn_kernel(const u16* __restrict__ Q,
                                                      const u16* __restrict__ K,
                                                      const u16* __restrict__ VT,
                                                      u16* __restrict__ O) {
  __shared__ __align__(16) u16 LDS[16384];

  const int tid = threadIdx.x;
  const int wid = tid >> 6;
  const int lane = tid & 63;
  const int l31 = lane & 31;
  const int hi = lane >> 5;

  // XCD-bijective: all 16 q-tiles + 4 bh per XCD
  const int bi = blockIdx.x;
  const int xcd = bi & 7, j = bi >> 3;
  const int qt = j & 15;
  const int bh = xcd + 8 * (j >> 4);
  const int b = bh >> 4, h = bh & 15;

  const int q0 = qt * 128 + wid * 32;

  // Q fragments (B-operand): col q = l31, k-elems d = ks*16 + hi*8 .. +7
  bf16x8 qf[4];
  {
    const u16* qp = Q + (size_t)(b * SEQ + q0 + l31) * 1024 + h * 64 + hi * 8;
#pragma unroll
    for (int ks = 0; ks < 4; ks++) qf[ks] = *(const bf16x8*)(qp + ks * 16);
  }

  f32x16 of[2];
#pragma unroll
  for (int d = 0; d < 2; d++)
#pragma unroll
    for (int e = 0; e < 16; e++) of[d][e] = 0.f;
  float m_run = -3.0e38f, l_run = 0.f;

  // tile-invariant per-lane LDS read bases (byte ptrs into tile row l31)
  const char* rdB[4];
#pragma unroll
  for (int ks = 0; ks < 4; ks++)
    rdB[ks] = (const char*)LDS + l31 * 128 + ((((2 * ks + hi) ^ (lane & 7))) << 4);

  // staging: wave w stages rows 8w..8w+7 (+32), pre-swizzled source column
  const int r0 = tid >> 3;
  const int srcc = ((tid & 7) ^ (r0 & 7)) << 3;
  const u16* gK = K + (size_t)(b * SEQ + r0) * 1024 + h * 64 + srcc;
  const u16* gV = VT + (size_t)(h * 64 + r0) * 4096 + b * SEQ + srcc;
  u16* lK = LDS + wid * 512;
  u16* lV = LDS + 8192 + wid * 512;

  auto stageK = [&](int t, int par) {
    const u16* sk = gK + (size_t)t * 64 * 1024;
    gload_lds16(sk, lK + par * 4096);
    gload_lds16(sk + (size_t)32 * 1024, lK + par * 4096 + 2048);
  };
  auto stageV = [&](int t, int par) {
    const u16* sv = gV + t * 64;
    gload_lds16(sv, lV + par * 4096);
    gload_lds16(sv + (size_t)32 * 4096, lV + par * 4096 + 2048);
  };

  // QK^T for one tile into sn; kbyte = K-buffer byte offset {0, 8192}
  auto qk = [&](f32x16 (&sn)[2], int kbyte) {
#pragma unroll
    for (int kb = 0; kb < 2; kb++)
#pragma unroll
      for (int e = 0; e < 16; e++) sn[kb][e] = 0.f;
    __builtin_amdgcn_s_setprio(1);
#pragma unroll
    for (int kb = 0; kb < 2; kb++)
#pragma unroll
      for (int ks = 0; ks < 4; ks++) {
        bf16x8 kf = *(const bf16x8*)(rdB[ks] + kbyte + kb * 4096);
        sn[kb] = __builtin_amdgcn_mfma_f32_32x32x16_bf16(kf, qf[ks], sn[kb], 0, 0, 0);
      }
    __builtin_amdgcn_s_setprio(0);
  };

  // softmax + PV for the tile whose scores are in sc; vbyte ∈ {0, 8192}
  auto smpv = [&](f32x16 (&sc)[2], int vbyte) {
    // hoist V loads (independent of softmax)
    bf16x8 vf0[4], vf1[4];
#pragma unroll
    for (int ks = 0; ks < 4; ks++) {
      vf0[ks] = *(const bf16x8*)(rdB[ks] + 16384 + vbyte);
      vf1[ks] = *(const bf16x8*)(rdB[ks] + 16384 + vbyte + 4096);
    }

    // tree max over 32 scores (4 parallel chains)
    float a0 = sc[0][0], a1 = sc[0][1], a2 = sc[0][2], a3 = sc[0][3];
#pragma unroll
    for (int e = 4; e < 16; e += 4) {
      a0 = fmaxf(a0, sc[0][e]);     a1 = fmaxf(a1, sc[0][e + 1]);
      a2 = fmaxf(a2, sc[0][e + 2]); a3 = fmaxf(a3, sc[0][e + 3]);
    }
#pragma unroll
    for (int e = 0; e < 16; e += 4) {
      a0 = fmaxf(a0, sc[1][e]);     a1 = fmaxf(a1, sc[1][e + 1]);
      a2 = fmaxf(a2, sc[1][e + 2]); a3 = fmaxf(a3, sc[1][e + 3]);
    }
    float tmax = fmaxf(fmaxf(a0, a1), fmaxf(a2, a3));
    tmax = fmaxf(tmax, __shfl_xor(tmax, 32));

    if (!__all(tmax <= m_run + DEFER_THR)) {   // defer-max (T13)
      const float m_new = fmaxf(m_run, tmax);
      const float esc = fast_exp2(m_run - m_new);
      l_run *= esc;
#pragma unroll
      for (int r = 0; r < 16; r++) {
        const int qof = (r & 3) + 8 * (r >> 2) + 4 * hi;
        const float e = __shfl(esc, qof);
        of[0][r] *= e;
        of[1][r] *= e;
      }
      m_run = m_new;
    }

    // p = exp2(s - m); psum via 4 parallel chains
    float s0 = 0.f, s1 = 0.f, s2 = 0.f, s3 = 0.f;
#pragma unroll
    for (int kb = 0; kb < 2; kb++)
#pragma unroll
      for (int e = 0; e < 16; e += 4) {
        float p0 = fast_exp2(sc[kb][e] - m_run);
        float p1 = fast_exp2(sc[kb][e + 1] - m_run);
        float p2 = fast_exp2(sc[kb][e + 2] - m_run);
        float p3 = fast_exp2(sc[kb][e + 3] - m_run);
        sc[kb][e] = p0; sc[kb][e + 1] = p1; sc[kb][e + 2] = p2; sc[kb][e + 3] = p3;
        s0 += p0; s1 += p1; s2 += p2; s3 += p3;
      }
    l_run += (s0 + s1) + (s2 + s3);

    // pack P to bf16 A-fragments in-register (cvt_pk + shfl_xor exchange)
    bf16x8 pa[4];
#pragma unroll
    for (int kb = 0; kb < 2; kb++) {
      uint32_t c0 = cvtpk(sc[kb][0],  sc[kb][1]);
      uint32_t c1 = cvtpk(sc[kb][2],  sc[kb][3]);
      uint32_t c2 = cvtpk(sc[kb][4],  sc[kb][5]);
      uint32_t c3 = cvtpk(sc[kb][6],  sc[kb][7]);
      uint32_t c4 = cvtpk(sc[kb][8],  sc[kb][9]);
      uint32_t c5 = cvtpk(sc[kb][10], sc[kb][11]);
      uint32_t c6 = cvtpk(sc[kb][12], sc[kb][13]);
      uint32_t c7 = cvtpk(sc[kb][14], sc[kb][15]);
      swap_pair(c0, c2, hi);
      swap_pair(c1, c3, hi);
      swap_pair(c4, c6, hi);
      swap_pair(c5, c7, hi);
      union { bf16x8 v; uint32_t d[4]; } u0, u1;
      u0.d[0] = c0; u0.d[1] = c1; u0.d[2] = c2; u0.d[3] = c3;
      u1.d[0] = c4; u1.d[1] = c5; u1.d[2] = c6; u1.d[3] = c7;
      pa[2 * kb] = u0.v;
      pa[2 * kb + 1] = u1.v;
    }

    // O += P (A) x V (B)
    __builtin_amdgcn_s_setprio(1);
#pragma unroll
    for (int ks = 0; ks < 4; ks++) {
      of[0] = __builtin_amdgcn_mfma_f32_32x32x16_bf16(pa[ks], vf0[ks], of[0], 0, 0, 0);
      of[1] = __builtin_amdgcn_mfma_f32_32x32x16_bf16(pa[ks], vf1[ks], of[1], 0, 0, 0);
    }
    __builtin_amdgcn_s_setprio(0);
  };

  f32x16 sA[2], sB[2];

  // prologue: K(0)->Kb0, K(1)->Kb1, V(0)->Vb0; S(0) -> sA
  stageK(0, 0); stageK(1, 1); stageV(0, 0);
  __syncthreads();
  qk(sA, 0);

  // steady state: iter t does {stage K(t+2),V(t+1); QK(t+1); softmax+PV(t)}
#pragma unroll 1
  for (int t = 0; t < 30; t += 2) {
    __syncthreads();                 // drains K(t+1), V(t)
    stageK(t + 2, 0); stageV(t + 1, 1);
    qk(sB, 8192);                    // QK(t+1) from Kb1
    smpv(sA, 0);                     // tile t, V from Vb0

    __syncthreads();                 // drains K(t+2), V(t+1)
    stageK(t + 3, 1); stageV(t + 2, 0);
    qk(sA, 0);                       // QK(t+2) from Kb0
    smpv(sB, 8192);                  // tile t+1, V from Vb1
  }
  // iter 30: no K(32)
  __syncthreads();
  stageV(31, 1);
  qk(sB, 8192);                      // QK(31)
  smpv(sA, 0);                       // tile 30
  // iter 31 (epilogue)
  __syncthreads();
  smpv(sB, 8192);                    // tile 31

  // final row-sum across the lane^32 pair, then normalize + write
  const float lsum = l_run + __shfl_xor(l_run, 32);
  const float linv = 1.f / lsum;

#pragma unroll
  for (int r = 0; r < 16; r++) {
    const int qof = (r & 3) + 8 * (r >> 2) + 4 * hi;
    const float li = __shfl(linv, qof);
    u16* op = O + (size_t)(b * SEQ + q0 + qof) * 1024 + h * 64 + l31;
    op[0]  = f2bf(of[0][r] * li);
    op[32] = f2bf(of[1][r] * li);
  }
}

// ---------------- launch ----------------
extern "C" void kernel_launch(void* const* d_in, const int* in_sizes, int n_in,
                              void* d_out, int out_size, void* d_ws, size_t ws_size,
                              hipStream_t stream) {
  const float* x   = (const float*)d_in[0];
  const float* z   = (const float*)d_in[1];
  const float* Wq  = (const float*)d_in[2];
  const float* Wkv = (const float*)d_in[3];
  const float* Wo  = (const float*)d_in[4];
  float* out = (float*)d_out;

  char* ws = (char*)d_ws;
  const size_t MB = 1024ull * 1024ull;
  u16* xb   = (u16*)(ws + 0);        // 8 MB  [4096][1024]
  u16* zb   = (u16*)(ws + 8 * MB);   // 4 MB  [4096][512]
  u16* Wqb  = (u16*)(ws + 12 * MB);  // 2 MB
  u16* Wkvb = (u16*)(ws + 14 * MB);  // 2 MB
  u16* Wob  = (u16*)(ws + 16 * MB);  // 2 MB
  u16* Qb   = (u16*)(ws + 18 * MB);  // 8 MB  [4096][1024] (pre-scaled, log2 domain)
  u16* Kb   = (u16*)(ws + 26 * MB);  // 8 MB  [4096][1024]
  u16* VTb  = (u16*)(ws + 34 * MB);  // 8 MB  [1024][4096]
  u16* Ob   = (u16*)(ws + 42 * MB);  // 8 MB  [4096][1024]

  cvt5_kernel<<<2048, 256, 0, stream>>>(x, z, Wq, Wkv, Wo, xb, zb, Wqb, Wkvb, Wob);

  qkv_gemm<<<768, 256, 0, stream>>>(xb, zb, Wqb, Wkvb, Qb, Kb, VTb);

  attn_kernel<<<512, 256, 0, stream>>>(Qb, Kb, VTb, Ob);

  o_gemm<<<dim3(16, 32), 256, 0, stream>>>(Ob, Wob, out);
}